// Round 3
// baseline (312.127 us; speedup 1.0000x reference)
//
#include <hip/hip_runtime.h>
#include <math.h>

#define NBINS 31
#define NSLOT 32        // 31 real bins + slot 31 = dummy sink (invalid / out-of-range, pk=0)
#define NCOPIES 128     // one private copy per THREAD PAIR (even lane is the sole writer)
#define BLOCK 256
#define GRID 2048       // 8 blocks/CU (LDS ~18.4KB), fully resident, one round

// Packed LDS histogram cell (u32): bits[31:25] = count, bits[24:0] = sum of
// |pred-target| in 2^-15 fixed point. Per pair-cell worst case: 64 elements
// (32/thread * 2), count <= 64 < 127; sum <= 64 * ~20K ~= 1.3M << 2^25.
//
// R3 history: bin-major layout (conflict-free, 4.4M -> 139K) + batched asm RMW
// was 48us at 33% occupancy. L3-resident dispatches ran NO faster than
// HBM-cold ones -> not load-latency-bound; bound by per-wave serial chain
// (LDS RMW wait + VALU issue) with only 4 waves/SIMD to overlap. R2's deep
// register pipeline spilled (VGPR stayed 52, 4x regression). This round:
// HALVE s_hist (copy per thread pair, even lane merges via DPP xor-1 swap +
// 8-wide batched RMW) -> 8 blocks/CU = 32 waves/CU (all wave slots), TLP does
// the latency hiding. No register pipeline.
#define CNT_SHIFT 25
#define SUM_MASK  0x1FFFFFFu
#define FIX_SCALE 32768.0f

// Workspace layout (4-byte units): [0..30] float bin sums, [64..94] uint bin
// counts, [128] uint total_valid, [129] uint ticket.

__device__ __forceinline__ unsigned xor1(unsigned x)
{
    // quad_perm [1,0,3,2]: swap values between the two lanes of each pair.
    // Pure VALU (DPP) — does not touch the LDS pipe, no wait needed.
    return (unsigned)__builtin_amdgcn_update_dpp(0, (int)x, 0xB1, 0xF, 0xF, true);
}

__device__ __forceinline__ void prep(float p, float t, unsigned hbase, bool inb,
                                     unsigned& addr, unsigned& pk, unsigned& nvalid)
{
    nvalid += (inb && t != -1.0f) ? 1u : 0u;
    // in-range: expm1(t) >= 0  <=>  t >= 0 (monotone), and implies valid.
    bool ok = inb && (t >= 0.0f);
    // Fast expm1 for binning only (~1 ULP): boundary misbins affect O(100)
    // of 16.7M samples -> loss delta ~1e-7 (accepted in prior rounds).
    float nat = __expf(t) - 1.0f;
    unsigned b = (unsigned)(int)fminf(nat, 30.0f);   // ok-path: nat>=0, trunc==floor
    unsigned pkv = (1u << CNT_SHIFT)
                 | (unsigned)(fabsf(p - t) * FIX_SCALE + 0.5f);
    pk   = ok ? pkv : 0u;
    addr = hbase + ((ok ? b : 31u) << 9);            // bin stride = 128 copies * 4B
}

// 8 elements (this thread's 4 + partner's 4) -> one batched RMW by the even
// lane: 8 ds_reads, ONE lgkm wait, 8 adds, 8 ds_writes. Aliasing is fixed in
// registers so the LAST write to any address carries the full sum:
//  - within each 4-group: prefix chain s_j = k_j + s_{latest earlier dup}
//  - across groups (partner group B writes after own group A): each B slot
//    adds the latest matching A slot's s. In-order LDS pipe => last write wins.
__device__ __forceinline__ void packet_pair(float4 p, float4 t, unsigned hbase,
                                            bool inb, bool evenlane, unsigned& nvalid)
{
    unsigned a0, a1, a2, a3, k0, k1, k2, k3;
    prep(p.x, t.x, hbase, inb, a0, k0, nvalid);
    prep(p.y, t.y, hbase, inb, a1, k1, nvalid);
    prep(p.z, t.z, hbase, inb, a2, k2, nvalid);
    prep(p.w, t.w, hbase, inb, a3, k3, nvalid);

    // intra-group alias chain
    unsigned s0 = k0;
    unsigned s1 = k1 + (a1 == a0 ? s0 : 0u);
    unsigned s2 = k2 + (a2 == a1 ? s1 : (a2 == a0 ? s0 : 0u));
    unsigned s3 = k3 + (a3 == a2 ? s2 : (a3 == a1 ? s1 : (a3 == a0 ? s0 : 0u)));

    // exchange with partner lane (all lanes active here)
    unsigned qa0 = xor1(a0), qa1 = xor1(a1), qa2 = xor1(a2), qa3 = xor1(a3);
    unsigned qs0 = xor1(s0), qs1 = xor1(s1), qs2 = xor1(s2), qs3 = xor1(s3);

    if (evenlane) {
        unsigned r0, r1, r2, r3, r4, r5, r6, r7;
        asm volatile(
            "ds_read_b32 %0, %8\n\t"
            "ds_read_b32 %1, %9\n\t"
            "ds_read_b32 %2, %10\n\t"
            "ds_read_b32 %3, %11\n\t"
            "ds_read_b32 %4, %12\n\t"
            "ds_read_b32 %5, %13\n\t"
            "ds_read_b32 %6, %14\n\t"
            "ds_read_b32 %7, %15"
            : "=&v"(r0), "=&v"(r1), "=&v"(r2), "=&v"(r3),
              "=&v"(r4), "=&v"(r5), "=&v"(r6), "=&v"(r7)
            : "v"(a0), "v"(a1), "v"(a2), "v"(a3),
              "v"(qa0), "v"(qa1), "v"(qa2), "v"(qa3));

        // cross-group correction (overlaps the ds_read latency): B_j takes the
        // LATEST matching A slot (A writes issue before B writes below).
        qs0 += (qa0 == a3 ? s3 : (qa0 == a2 ? s2 : (qa0 == a1 ? s1 : (qa0 == a0 ? s0 : 0u))));
        qs1 += (qa1 == a3 ? s3 : (qa1 == a2 ? s2 : (qa1 == a1 ? s1 : (qa1 == a0 ? s0 : 0u))));
        qs2 += (qa2 == a3 ? s3 : (qa2 == a2 ? s2 : (qa2 == a1 ? s1 : (qa2 == a0 ? s0 : 0u))));
        qs3 += (qa3 == a3 ? s3 : (qa3 == a2 ? s2 : (qa3 == a1 ? s1 : (qa3 == a0 ? s0 : 0u))));

        asm volatile(
            "s_waitcnt lgkmcnt(0)\n\t"
            "v_add_u32 %0, %0, %8\n\t"
            "v_add_u32 %1, %1, %9\n\t"
            "v_add_u32 %2, %2, %10\n\t"
            "v_add_u32 %3, %3, %11\n\t"
            "v_add_u32 %4, %4, %12\n\t"
            "v_add_u32 %5, %5, %13\n\t"
            "v_add_u32 %6, %6, %14\n\t"
            "v_add_u32 %7, %7, %15\n\t"
            "ds_write_b32 %16, %0\n\t"
            "ds_write_b32 %17, %1\n\t"
            "ds_write_b32 %18, %2\n\t"
            "ds_write_b32 %19, %3\n\t"
            "ds_write_b32 %20, %4\n\t"
            "ds_write_b32 %21, %5\n\t"
            "ds_write_b32 %22, %6\n\t"
            "ds_write_b32 %23, %7"
            : "+v"(r0), "+v"(r1), "+v"(r2), "+v"(r3),
              "+v"(r4), "+v"(r5), "+v"(r6), "+v"(r7)
            : "v"(s0), "v"(s1), "v"(s2), "v"(s3),
              "v"(qs0), "v"(qs1), "v"(qs2), "v"(qs3),
              "v"(a0), "v"(a1), "v"(a2), "v"(a3),
              "v"(qa0), "v"(qa1), "v"(qa2), "v"(qa3)
            : "memory");
    }
}

__global__ __launch_bounds__(BLOCK) void zero_ws_kernel(unsigned* ws)
{
    int t = threadIdx.x;
    if (t < 192) ws[t] = 0u;
}

__global__ __launch_bounds__(BLOCK, 8) void hist_kernel(
    const float* __restrict__ pred, const float* __restrict__ target, int n,
    float* __restrict__ g_sums, unsigned* __restrict__ g_cnts,
    unsigned* __restrict__ g_total, unsigned* __restrict__ g_ticket,
    float* __restrict__ out)
{
    __shared__ unsigned s_hist[NSLOT * NCOPIES];  // bin-major: [slot][pair], 16 KB
    __shared__ float    p_sum[NBINS * 8];
    __shared__ unsigned p_cnt[NBINS * 8];
    __shared__ unsigned s_tot[BLOCK / 64];
    __shared__ unsigned s_last;

    const int tid = threadIdx.x;
    {   // zero 4096 words as 1024 uint4
        uint4 z = make_uint4(0u, 0u, 0u, 0u);
        uint4* h4 = (uint4*)s_hist;
        #pragma unroll
        for (int k = 0; k < (NSLOT * NCOPIES / 4) / BLOCK; ++k) h4[tid + k * BLOCK] = z;
    }
    __syncthreads();

    // LDS byte address of this PAIR's column (low 32 bits of the flat shared
    // address == LDS offset: shared aperture is 2^32-aligned on gfx9+).
    const unsigned hbase = (unsigned)(uintptr_t)(void*)s_hist + ((unsigned)(tid >> 1) << 2);
    const int  lane1    = tid & 1;
    const bool evenlane = (lane1 == 0);
    unsigned nvalid = 0;

    const int n4 = n >> 2;
    const float4* __restrict__ pred4 = (const float4*)pred;
    const float4* __restrict__ targ4 = (const float4*)target;
    const int st = gridDim.x * BLOCK;
    const int i0 = blockIdx.x * BLOCK + tid;

    // trip count uniform within each pair: iterate while the EVEN lane's index
    // is in range; the odd lane's possibly-OOB element is masked via inb.
    for (int i = i0; (i - lane1) < n4; i += st) {
        bool inb = (i < n4);
        int  c   = inb ? i : 0;                      // clamped load, masked in prep
        float4 p = pred4[c];
        float4 t = targ4[c];
        packet_pair(p, t, hbase, inb, evenlane, nvalid);
    }
    // scalar tail (n % 4 leftovers: at most 3 elements device-wide) -> straight
    // to global accumulators, natural units.
    for (int i = (n4 << 2) + i0; i < n; i += st) {
        float p = pred[i], t = target[i];
        if (t != -1.0f) {
            atomicAdd(g_total, 1u);
            if (t >= 0.0f) {
                float nat = __expf(t) - 1.0f;
                int b = (int)fminf(nat, 30.0f);
                atomicAdd(&g_sums[b], fabsf(p - t));
                atomicAdd(&g_cnts[b], 1u);
            }
        }
    }
    // drain our asm ds_writes before the barrier (compiler doesn't track them)
    asm volatile("s_waitcnt lgkmcnt(0)" ::: "memory");
    __syncthreads();

    // Stage 1: 128 pair-copies -> 8 partials per bin (248 threads), uint4 reads
    if (tid < NBINS * 8) {
        const int b = tid >> 3, g = tid & 7;
        const uint4* row = (const uint4*)(s_hist + b * NCOPIES);
        float fs = 0.0f; unsigned cs = 0u;
        #pragma unroll
        for (int kk = 0; kk < 4; ++kk) {
            uint4 v = row[g + 8 * kk];
            cs += (v.x >> CNT_SHIFT) + (v.y >> CNT_SHIFT)
                + (v.z >> CNT_SHIFT) + (v.w >> CNT_SHIFT);
            fs += (float)(v.x & SUM_MASK) + (float)(v.y & SUM_MASK)
                + (float)(v.z & SUM_MASK) + (float)(v.w & SUM_MASK);
        }
        p_sum[tid] = fs;   // tid == b*8+g
        p_cnt[tid] = cs;
    }
    // valid count: shuffle-reduce per wave
    unsigned v = nvalid;
    #pragma unroll
    for (int off = 32; off >= 1; off >>= 1) v += __shfl_down(v, off, 64);
    if ((tid & 63) == 0) s_tot[tid >> 6] = v;
    __syncthreads();

    // Stage 2: 8 partials -> 1 per bin, then one global atomic per bin
    if (tid < NBINS) {
        float fs = 0.0f; unsigned cs = 0u;
        #pragma unroll
        for (int g = 0; g < 8; ++g) { fs += p_sum[tid * 8 + g]; cs += p_cnt[tid * 8 + g]; }
        atomicAdd(&g_sums[tid], fs * (1.0f / FIX_SCALE));
        atomicAdd(&g_cnts[tid], cs);
    }
    if (tid == 0) {
        unsigned tot = 0;
        #pragma unroll
        for (int w = 0; w < BLOCK / 64; ++w) tot += s_tot[w];
        atomicAdd(g_total, tot);
    }

    // -------- last-block finalize (replaces a 3rd kernel launch) --------
    __threadfence();                       // release: our atomics visible first
    __syncthreads();
    if (tid == 0)
        s_last = (atomicAdd(g_ticket, 1u) == (unsigned)gridDim.x - 1u) ? 1u : 0u;
    __syncthreads();
    if (s_last && tid < 64) {
        __threadfence();                   // acquire side of the ticket
        int lane = tid;
        float denom = fmaxf((float)atomicAdd(g_total, 0u), 1.0f);
        float contrib = 0.0f;
        if (lane < NBINS) {
            // atomicAdd(.,0) = coherent L2 read (bypasses L1/compiler caching)
            float fs = atomicAdd(&g_sums[lane], 0.0f);
            float freq = (float)atomicAdd(&g_cnts[lane], 0u) / denom;
            float w = 1.0f / (sqrtf(freq) + 1e-6f);   // ALPHA=0.5 -> sqrt
            contrib = fs * w;
        }
        #pragma unroll
        for (int off = 32; off >= 1; off >>= 1) contrib += __shfl_down(contrib, off, 64);
        if (lane == 0) *out = contrib / denom;
    }
}

extern "C" void kernel_launch(void* const* d_in, const int* in_sizes, int n_in,
                              void* d_out, int out_size, void* d_ws, size_t ws_size,
                              hipStream_t stream)
{
    const float* pred   = (const float*)d_in[0];
    const float* target = (const float*)d_in[1];
    float* out = (float*)d_out;
    int n = in_sizes[0];

    float*    g_sums   = (float*)d_ws;
    unsigned* g_cnts   = (unsigned*)d_ws + 64;
    unsigned* g_total  = (unsigned*)d_ws + 128;
    unsigned* g_ticket = (unsigned*)d_ws + 129;

    zero_ws_kernel<<<1, BLOCK, 0, stream>>>((unsigned*)d_ws);

    hist_kernel<<<GRID, BLOCK, 0, stream>>>(pred, target, n, g_sums, g_cnts,
                                            g_total, g_ticket, out);
}

// Round 4
// 266.294 us; speedup vs baseline: 1.1721x; 1.1721x over previous
//
#include <hip/hip_runtime.h>
#include <math.h>

#define NBINS 31
#define NSLOT 32        // 31 real bins + slot 31 = dummy sink (invalid / out-of-range, pk=0)
#define NCOPIES 256     // one private copy per thread -> NO atomics, no write races
#define BLOCK 256
#define GRID 1024       // 4 blocks/CU (LDS-capped), fully resident, one round

// Packed LDS histogram cell (u32): bits[31:25] = count, bits[24:0] = sum of
// |pred-target| in 2^-15 fixed point. Per thread-copy-bin worst case: 64
// elements, base <= ~1 -> sum_fixed <= ~2.1M << 2^25; count <= 64 < 128.
//
// Ledger: R1 = 48us (bin-major conflict-free layout + 4-wide batched asm RMW,
// 33% occ). R2 (deep reg pipeline) & R3 (pair-copies @ 8 blocks/CU) both
// REGRESSED via allocator spills (VGPR 52->52/20, VALU 6-7%).
// R4 root cause found: the in-loop ds_write asm carried a "memory" clobber ->
// LLVM could never hoist next-iteration global loads across it -> every packet
// paid FULL serialized vmem latency (~6500 of 7200 cyc/packet). Fix: remove
// the clobber (volatile asm keeps program order among asm blocks; the only
// other LDS accesses are fenced by the final drain asm, which KEEPS "memory",
// + __syncthreads). Plus a clean uniform-trip loop (benched shape: T=16, no
// clamps) so the ping-pong distance-2 prefetch can actually materialize.
#define CNT_SHIFT 25
#define SUM_MASK  0x1FFFFFFu
#define FIX_SCALE 32768.0f

// Workspace layout (4-byte units): [0..30] float bin sums, [64..94] uint bin
// counts, [128] uint total_valid, [129] uint ticket.

__device__ __forceinline__ void prep(float p, float t, unsigned hbase,
                                     unsigned& addr, unsigned& pk, unsigned& nvalid)
{
    nvalid += (t != -1.0f) ? 1u : 0u;
    // in-range: expm1(t) >= 0  <=>  t >= 0 (monotone), and implies valid.
    bool ok = (t >= 0.0f);
    // Fast expm1 for binning only (~1 ULP): boundary misbins affect O(100)
    // of 16.7M samples -> loss delta ~1e-7 (accepted in prior rounds).
    float nat = __expf(t) - 1.0f;
    unsigned b = (unsigned)(int)fminf(nat, 30.0f);   // ok-path: nat>=0, trunc==floor
    unsigned pkv = (1u << CNT_SHIFT)
                 | (unsigned)(fabsf(p - t) * FIX_SCALE + 0.5f);
    pk   = ok ? pkv : 0u;
    addr = hbase + ((ok ? b : 31u) << 10);           // bin stride = 256 copies * 4B
}

// Process 4 elements: one LDS-latency wait instead of four. Aliasing within
// the packet is fixed in registers: s_j = pk_j + s_{latest earlier dup}, and
// ds writes issue in order (in-order LDS pipe, later write wins) so the last
// write to any address carries the full sum. Duplicate/invalid slots that
// still collide are all pk=0 -> lost updates lose only zero.
// NOTE: no "memory" clobber here — deliberate. volatile asm blocks keep
// program order among themselves; global loads MUST be free to hoist across.
__device__ __forceinline__ void packet(float4 p, float4 t, unsigned hbase,
                                       unsigned& nvalid)
{
    unsigned a0, a1, a2, a3, k0, k1, k2, k3;
    prep(p.x, t.x, hbase, a0, k0, nvalid);
    prep(p.y, t.y, hbase, a1, k1, nvalid);
    prep(p.z, t.z, hbase, a2, k2, nvalid);
    prep(p.w, t.w, hbase, a3, k3, nvalid);

    unsigned r0, r1, r2, r3;
    asm volatile(
        "ds_read_b32 %0, %4\n\t"
        "ds_read_b32 %1, %5\n\t"
        "ds_read_b32 %2, %6\n\t"
        "ds_read_b32 %3, %7"
        : "=&v"(r0), "=&v"(r1), "=&v"(r2), "=&v"(r3)
        : "v"(a0), "v"(a1), "v"(a2), "v"(a3));

    // alias-correction prefix chain (overlaps the ds_read latency)
    unsigned s0 = k0;
    unsigned s1 = k1 + (a1 == a0 ? s0 : 0u);
    unsigned s2 = k2 + (a2 == a1 ? s1 : (a2 == a0 ? s0 : 0u));
    unsigned s3 = k3 + (a3 == a2 ? s2 : (a3 == a1 ? s1 : (a3 == a0 ? s0 : 0u)));

    asm volatile(
        "s_waitcnt lgkmcnt(0)\n\t"
        "v_add_u32 %0, %0, %4\n\t"
        "v_add_u32 %1, %1, %5\n\t"
        "v_add_u32 %2, %2, %6\n\t"
        "v_add_u32 %3, %3, %7\n\t"
        "ds_write_b32 %8, %0\n\t"
        "ds_write_b32 %9, %1\n\t"
        "ds_write_b32 %10, %2\n\t"
        "ds_write_b32 %11, %3"
        : "+v"(r0), "+v"(r1), "+v"(r2), "+v"(r3)
        : "v"(s0), "v"(s1), "v"(s2), "v"(s3),
          "v"(a0), "v"(a1), "v"(a2), "v"(a3));
}

__global__ __launch_bounds__(BLOCK) void zero_ws_kernel(unsigned* ws)
{
    int t = threadIdx.x;
    if (t < 192) ws[t] = 0u;
}

__global__ __launch_bounds__(BLOCK, 4) void hist_kernel(
    const float* __restrict__ pred, const float* __restrict__ target, int n,
    float* __restrict__ g_sums, unsigned* __restrict__ g_cnts,
    unsigned* __restrict__ g_total, unsigned* __restrict__ g_ticket,
    float* __restrict__ out)
{
    __shared__ unsigned s_hist[NSLOT * NCOPIES];  // bin-major: [slot][copy], bank = tid%32
    __shared__ float    p_sum[NBINS * 8];
    __shared__ unsigned p_cnt[NBINS * 8];
    __shared__ unsigned s_tot[BLOCK / 64];
    __shared__ unsigned s_last;

    const int tid = threadIdx.x;
    {   // zero 8192 words as 2048 uint4
        uint4 z = make_uint4(0u, 0u, 0u, 0u);
        uint4* h4 = (uint4*)s_hist;
        #pragma unroll
        for (int k = 0; k < (NSLOT * NCOPIES / 4) / BLOCK; ++k) h4[tid + k * BLOCK] = z;
    }
    __syncthreads();

    // LDS byte address of this thread's column (low 32 bits of the flat
    // shared address == LDS offset: shared aperture is 2^32-aligned on gfx9+).
    const unsigned hbase = (unsigned)(uintptr_t)(void*)s_hist + ((unsigned)tid << 2);
    unsigned nvalid = 0;

    const int n4 = n >> 2;
    const float4* __restrict__ pred4 = (const float4*)pred;
    const float4* __restrict__ targ4 = (const float4*)target;
    const int st = gridDim.x * BLOCK;
    const int i0 = blockIdx.x * BLOCK + tid;
    const int T  = n4 / st;                       // uniform trip count if n4%st==0

    if ((n4 % st) == 0 && (n & 3) == 0 && T >= 2 && (T & 1) == 0) {
        // -------- clean path (benched shape: T=16) --------
        // straight-line ping-pong, prefetch distance 2, no clamps, no tail
        float4 pA = pred4[i0],      tA = targ4[i0];
        float4 pB = pred4[i0 + st], tB = targ4[i0 + st];
        int i = i0 + 2 * st;
        for (int k = 0; k < T - 2; k += 2, i += 2 * st) {
            float4 pNA = pred4[i],      tNA = targ4[i];
            float4 pNB = pred4[i + st], tNB = targ4[i + st];
            packet(pA, tA, hbase, nvalid);
            packet(pB, tB, hbase, nvalid);
            pA = pNA; tA = tNA; pB = pNB; tB = tNB;
        }
        packet(pA, tA, hbase, nvalid);            // epilogue
        packet(pB, tB, hbase, nvalid);
    } else {
        // -------- generic fallback (correctness only) --------
        for (int i = i0; i < n4; i += st) {
            float4 p = pred4[i];
            float4 t = targ4[i];
            packet(p, t, hbase, nvalid);
        }
        for (int i = (n4 << 2) + i0; i < n; i += st) {   // n%4 leftovers
            float p = pred[i], t = target[i];
            if (t != -1.0f) {
                atomicAdd(g_total, 1u);
                if (t >= 0.0f) {
                    float nat = __expf(t) - 1.0f;
                    int b = (int)fminf(nat, 30.0f);
                    atomicAdd(&g_sums[b], fabsf(p - t));
                    atomicAdd(&g_cnts[b], 1u);
                }
            }
        }
    }
    // drain our asm ds_writes before the barrier; THIS one keeps "memory"
    // (fences the asm LDS state against the reduction reads below)
    asm volatile("s_waitcnt lgkmcnt(0)" ::: "memory");
    __syncthreads();

    // Stage 1: 256 copies -> 8 partials per bin (248 threads), uint4 reads
    if (tid < NBINS * 8) {
        const int b = tid >> 3, g = tid & 7;
        const uint4* row = (const uint4*)(s_hist + b * NCOPIES);
        float fs = 0.0f; unsigned cs = 0u;
        #pragma unroll
        for (int kk = 0; kk < 8; ++kk) {
            uint4 v = row[g + 8 * kk];
            cs += (v.x >> CNT_SHIFT) + (v.y >> CNT_SHIFT)
                + (v.z >> CNT_SHIFT) + (v.w >> CNT_SHIFT);
            fs += (float)(v.x & SUM_MASK) + (float)(v.y & SUM_MASK)
                + (float)(v.z & SUM_MASK) + (float)(v.w & SUM_MASK);
        }
        p_sum[tid] = fs;   // tid == b*8+g
        p_cnt[tid] = cs;
    }
    // valid count: shuffle-reduce per wave
    unsigned v = nvalid;
    #pragma unroll
    for (int off = 32; off >= 1; off >>= 1) v += __shfl_down(v, off, 64);
    if ((tid & 63) == 0) s_tot[tid >> 6] = v;
    __syncthreads();

    // Stage 2: 8 partials -> 1 per bin, then one global atomic per bin
    if (tid < NBINS) {
        float fs = 0.0f; unsigned cs = 0u;
        #pragma unroll
        for (int g = 0; g < 8; ++g) { fs += p_sum[tid * 8 + g]; cs += p_cnt[tid * 8 + g]; }
        atomicAdd(&g_sums[tid], fs * (1.0f / FIX_SCALE));
        atomicAdd(&g_cnts[tid], cs);
    }
    if (tid == 0) {
        unsigned tot = 0;
        #pragma unroll
        for (int w = 0; w < BLOCK / 64; ++w) tot += s_tot[w];
        atomicAdd(g_total, tot);
    }

    // -------- last-block finalize (replaces a 3rd kernel launch) --------
    __threadfence();                       // release: our atomics visible first
    __syncthreads();
    if (tid == 0)
        s_last = (atomicAdd(g_ticket, 1u) == (unsigned)gridDim.x - 1u) ? 1u : 0u;
    __syncthreads();
    if (s_last && tid < 64) {
        __threadfence();                   // acquire side of the ticket
        int lane = tid;
        float denom = fmaxf((float)atomicAdd(g_total, 0u), 1.0f);
        float contrib = 0.0f;
        if (lane < NBINS) {
            // atomicAdd(.,0) = coherent L2 read (bypasses L1/compiler caching)
            float fs = atomicAdd(&g_sums[lane], 0.0f);
            float freq = (float)atomicAdd(&g_cnts[lane], 0u) / denom;
            float w = 1.0f / (sqrtf(freq) + 1e-6f);   // ALPHA=0.5 -> sqrt
            contrib = fs * w;
        }
        #pragma unroll
        for (int off = 32; off >= 1; off >>= 1) contrib += __shfl_down(contrib, off, 64);
        if (lane == 0) *out = contrib / denom;
    }
}

extern "C" void kernel_launch(void* const* d_in, const int* in_sizes, int n_in,
                              void* d_out, int out_size, void* d_ws, size_t ws_size,
                              hipStream_t stream)
{
    const float* pred   = (const float*)d_in[0];
    const float* target = (const float*)d_in[1];
    float* out = (float*)d_out;
    int n = in_sizes[0];

    float*    g_sums   = (float*)d_ws;
    unsigned* g_cnts   = (unsigned*)d_ws + 64;
    unsigned* g_total  = (unsigned*)d_ws + 128;
    unsigned* g_ticket = (unsigned*)d_ws + 129;

    zero_ws_kernel<<<1, BLOCK, 0, stream>>>((unsigned*)d_ws);

    hist_kernel<<<GRID, BLOCK, 0, stream>>>(pred, target, n, g_sums, g_cnts,
                                            g_total, g_ticket, out);
}

// Round 5
// 147.720 us; speedup vs baseline: 2.1130x; 1.8027x over previous
//
#include <hip/hip_runtime.h>
#include <math.h>

#define NBINS 31
#define NSLOT 32        // 31 real bins + slot 31 = dummy sink (invalid / out-of-range, pk=0)
#define NCOPIES 256     // one private copy per thread -> NO atomics, no write races
#define BLOCK 256
#define GRID 768        // 3 blocks/CU (LDS ~51KB), fully resident, one round

// Packed LDS histogram cell (u32): bits[31:25] = count, bits[24:0] = sum of
// |pred-target| in 2^-15 fixed point. Per thread-copy-bin worst case: ~86
// elements, count < 128; sum <= ~2.8M << 2^25.
//
// Ledger: R1 = 48us main loop (bin-major conflict-free hist + batched asm RMW).
// R2/R3 = spill regressions. R4 isolated TWO facts: (a) fused finalize's
// __threadfence() (1024 blocks x device fence) costs ~100us -> REVERTED to
// separate finalize kernel; (b) VGPR pinned at 52 even with a clean loop ->
// volatile inline asm blocks VMEM motion in the machine scheduler regardless
// of clobbers -> compiler-scheduled prefetch is impossible here.
// R5: place the loads MYSELF: __builtin_amdgcn_global_load_lds (async DMA to
// LDS, no VGPR round trip), double-buffered WAVE-PRIVATE staging (no barrier:
// each wave consumes only its own buffer), counted s_waitcnt vmcnt(2), read
// back via asm ds_read_b128 (+lgkmcnt inside the block, rule-18-safe).
// Global latency leaves the per-packet critical path entirely.
#define CNT_SHIFT 25
#define SUM_MASK  0x1FFFFFFu
#define FIX_SCALE 32768.0f

typedef float f4 __attribute__((ext_vector_type(4)));

// Workspace layout (4-byte units): [0..30] float bin sums, [64..94] uint bin
// counts, [128] uint total_valid.

__device__ __forceinline__ void prep(float p, float t, unsigned hbase,
                                     unsigned& addr, unsigned& pk, unsigned& nvalid)
{
    nvalid += (t != -1.0f) ? 1u : 0u;
    // in-range: expm1(t) >= 0  <=>  t >= 0 (monotone), and implies valid.
    bool ok = (t >= 0.0f);
    // Fast expm1 for binning only (~1 ULP): boundary misbins affect O(100)
    // of 16.7M samples -> loss delta ~1e-7 (accepted in prior rounds).
    float nat = __expf(t) - 1.0f;
    unsigned b = (unsigned)(int)fminf(nat, 30.0f);   // ok-path: nat>=0, trunc==floor
    unsigned pkv = (1u << CNT_SHIFT)
                 | (unsigned)(fabsf(p - t) * FIX_SCALE + 0.5f);
    pk   = ok ? pkv : 0u;
    addr = hbase + ((ok ? b : 31u) << 10);           // bin stride = 256 copies * 4B
}

// Process 4 elements: one LDS-latency wait instead of four. Aliasing within
// the packet is fixed in registers: s_j = pk_j + s_{latest earlier dup}; ds
// writes issue in order (in-order LDS pipe, later write wins) so the last
// write to any address carries the full sum. Invalid slots go to the dummy
// sink with pk=0. No "memory" clobbers in-loop (nothing compiler-visible to
// order against; final drain asm + __syncthreads fence the reduction).
__device__ __forceinline__ void packet(f4 p, f4 t, unsigned hbase,
                                       unsigned& nvalid)
{
    unsigned a0, a1, a2, a3, k0, k1, k2, k3;
    prep(p.x, t.x, hbase, a0, k0, nvalid);
    prep(p.y, t.y, hbase, a1, k1, nvalid);
    prep(p.z, t.z, hbase, a2, k2, nvalid);
    prep(p.w, t.w, hbase, a3, k3, nvalid);

    unsigned r0, r1, r2, r3;
    asm volatile(
        "ds_read_b32 %0, %4\n\t"
        "ds_read_b32 %1, %5\n\t"
        "ds_read_b32 %2, %6\n\t"
        "ds_read_b32 %3, %7"
        : "=&v"(r0), "=&v"(r1), "=&v"(r2), "=&v"(r3)
        : "v"(a0), "v"(a1), "v"(a2), "v"(a3));

    // alias-correction prefix chain (overlaps the ds_read latency)
    unsigned s0 = k0;
    unsigned s1 = k1 + (a1 == a0 ? s0 : 0u);
    unsigned s2 = k2 + (a2 == a1 ? s1 : (a2 == a0 ? s0 : 0u));
    unsigned s3 = k3 + (a3 == a2 ? s2 : (a3 == a1 ? s1 : (a3 == a0 ? s0 : 0u)));

    asm volatile(
        "s_waitcnt lgkmcnt(0)\n\t"
        "v_add_u32 %0, %0, %4\n\t"
        "v_add_u32 %1, %1, %5\n\t"
        "v_add_u32 %2, %2, %6\n\t"
        "v_add_u32 %3, %3, %7\n\t"
        "ds_write_b32 %8, %0\n\t"
        "ds_write_b32 %9, %1\n\t"
        "ds_write_b32 %10, %2\n\t"
        "ds_write_b32 %11, %3"
        : "+v"(r0), "+v"(r1), "+v"(r2), "+v"(r3)
        : "v"(s0), "v"(s1), "v"(s2), "v"(s3),
          "v"(a0), "v"(a1), "v"(a2), "v"(a3));
}

// async-stage one packet-index worth of pred+targ into this wave's buffer:
// lane L's 16B land at dst + L*16 (pred) and dst + 1024 + L*16 (targ).
// Global source address is per-lane; LDS dst must be wave-uniform (it is).
__device__ __forceinline__ void stage(unsigned* dst, const f4* p4, const f4* t4,
                                      int idx)
{
    __builtin_amdgcn_global_load_lds(
        (const __attribute__((address_space(1))) unsigned*)(const void*)(p4 + idx),
        (__attribute__((address_space(3))) unsigned*)dst, 16, 0, 0);
    __builtin_amdgcn_global_load_lds(
        (const __attribute__((address_space(1))) unsigned*)(const void*)(t4 + idx),
        (__attribute__((address_space(3))) unsigned*)(dst + 256), 16, 0, 0);
}

// read this lane's staged packet back: two b128 reads + wait INSIDE the asm
// (users depend on outputs -> cannot be hoisted past the wait; rule #18 safe)
__device__ __forceinline__ void unstage(unsigned sa, f4& pv, f4& tv)
{
    asm volatile(
        "ds_read_b128 %0, %2\n\t"
        "ds_read_b128 %1, %2 offset:1024\n\t"
        "s_waitcnt lgkmcnt(0)"
        : "=&v"(pv), "=&v"(tv)
        : "v"(sa));
}

__global__ __launch_bounds__(BLOCK) void zero_ws_kernel(unsigned* ws)
{
    int t = threadIdx.x;
    if (t < 192) ws[t] = 0u;
}

__global__ __launch_bounds__(BLOCK, 3) void hist_kernel(
    const float* __restrict__ pred, const float* __restrict__ target, int n,
    float* __restrict__ g_sums, unsigned* __restrict__ g_cnts,
    unsigned* __restrict__ g_total)
{
    __shared__ unsigned s_hist[NSLOT * NCOPIES];   // bin-major: [slot][copy], 32 KB
    __shared__ unsigned s_stage[2][BLOCK / 64][512]; // [buf][wave][2KB]: pred | targ
    __shared__ float    p_sum[NBINS * 8];
    __shared__ unsigned p_cnt[NBINS * 8];
    __shared__ unsigned s_tot[BLOCK / 64];

    const int tid = threadIdx.x;
    {   // zero 8192 hist words as 2048 uint4
        uint4 z = make_uint4(0u, 0u, 0u, 0u);
        uint4* h4 = (uint4*)s_hist;
        #pragma unroll
        for (int k = 0; k < (NSLOT * NCOPIES / 4) / BLOCK; ++k) h4[tid + k * BLOCK] = z;
    }
    __syncthreads();

    // LDS byte addresses (low 32 bits of flat shared addr == LDS offset on gfx9+)
    const unsigned hbase = (unsigned)(uintptr_t)(void*)s_hist + ((unsigned)tid << 2);
    const int lane = tid & 63, wv = tid >> 6;
    unsigned* stA = &s_stage[0][wv][0];
    unsigned* stB = &s_stage[1][wv][0];
    const unsigned saA = (unsigned)(uintptr_t)(void*)stA + ((unsigned)lane << 4);
    const unsigned saB = (unsigned)(uintptr_t)(void*)stB + ((unsigned)lane << 4);
    unsigned nvalid = 0;

    const int n4 = n >> 2;
    const f4* __restrict__ pred4 = (const f4*)pred;
    const f4* __restrict__ targ4 = (const f4*)target;
    const int st = GRID * BLOCK;
    const int i0 = blockIdx.x * BLOCK + tid;

    // clean path needs: vectorizable n, wave-uniform trip counts (n4 % 64 == 0)
    if ((n & 3) == 0 && (n4 & 63) == 0) {
        int i = i0;
        if (i < n4) {                                 // wave-uniform guard
            stage(stA, pred4, targ4, i);              // prologue: buf A in flight
            bool curA = true;
            for (; i + st < n4; i += st) {
                // issue next buf's DMA, then wait until only those 2 remain
                if (curA) stage(stB, pred4, targ4, i + st);
                else      stage(stA, pred4, targ4, i + st);
                asm volatile("s_waitcnt vmcnt(2)" ::: "memory");
                f4 pv, tv;
                unstage(curA ? saA : saB, pv, tv);
                packet(pv, tv, hbase, nvalid);
                curA = !curA;
            }
            asm volatile("s_waitcnt vmcnt(0)" ::: "memory");   // drain last buf
            f4 pv, tv;
            unstage(curA ? saA : saB, pv, tv);
            packet(pv, tv, hbase, nvalid);
        }
    } else {
        // -------- generic fallback (correctness only) --------
        for (int i = i0; i < n4; i += st) {
            f4 p = pred4[i];
            f4 t = targ4[i];
            packet(p, t, hbase, nvalid);
        }
        for (int i = (n4 << 2) + i0; i < n; i += st) {   // n%4 leftovers
            float p = pred[i], t = target[i];
            if (t != -1.0f) {
                atomicAdd(g_total, 1u);
                if (t >= 0.0f) {
                    float nat = __expf(t) - 1.0f;
                    int b = (int)fminf(nat, 30.0f);
                    atomicAdd(&g_sums[b], fabsf(p - t));
                    atomicAdd(&g_cnts[b], 1u);
                }
            }
        }
    }
    // drain asm ds_writes before the barrier; THIS one keeps "memory"
    // (fences the asm LDS state against the reduction reads below)
    asm volatile("s_waitcnt lgkmcnt(0)" ::: "memory");
    __syncthreads();

    // Stage 1: 256 copies -> 8 partials per bin (248 threads), uint4 reads
    if (tid < NBINS * 8) {
        const int b = tid >> 3, g = tid & 7;
        const uint4* row = (const uint4*)(s_hist + b * NCOPIES);
        float fs = 0.0f; unsigned cs = 0u;
        #pragma unroll
        for (int kk = 0; kk < 8; ++kk) {
            uint4 v = row[g + 8 * kk];
            cs += (v.x >> CNT_SHIFT) + (v.y >> CNT_SHIFT)
                + (v.z >> CNT_SHIFT) + (v.w >> CNT_SHIFT);
            fs += (float)(v.x & SUM_MASK) + (float)(v.y & SUM_MASK)
                + (float)(v.z & SUM_MASK) + (float)(v.w & SUM_MASK);
        }
        p_sum[tid] = fs;   // tid == b*8+g
        p_cnt[tid] = cs;
    }
    // valid count: shuffle-reduce per wave
    unsigned v = nvalid;
    #pragma unroll
    for (int off = 32; off >= 1; off >>= 1) v += __shfl_down(v, off, 64);
    if ((tid & 63) == 0) s_tot[tid >> 6] = v;
    __syncthreads();

    // Stage 2: 8 partials -> 1 per bin, then one global atomic per bin
    if (tid < NBINS) {
        float fs = 0.0f; unsigned cs = 0u;
        #pragma unroll
        for (int g = 0; g < 8; ++g) { fs += p_sum[tid * 8 + g]; cs += p_cnt[tid * 8 + g]; }
        atomicAdd(&g_sums[tid], fs * (1.0f / FIX_SCALE));
        atomicAdd(&g_cnts[tid], cs);
    }
    if (tid == 0) {
        unsigned tot = 0;
        #pragma unroll
        for (int w = 0; w < BLOCK / 64; ++w) tot += s_tot[w];
        atomicAdd(g_total, tot);
    }
}

__global__ void finalize_kernel(const float* __restrict__ g_sums,
                                const unsigned* __restrict__ g_cnts,
                                const unsigned* __restrict__ g_total,
                                float* __restrict__ out)
{
    int lane = threadIdx.x;  // 64 threads, one wave
    float denom = fmaxf((float)(*g_total), 1.0f);
    float contrib = 0.0f;
    if (lane < NBINS) {
        float freq = (float)g_cnts[lane] / denom;
        float w = 1.0f / (sqrtf(freq) + 1e-6f);   // ALPHA=0.5 -> sqrt
        contrib = g_sums[lane] * w;
    }
    #pragma unroll
    for (int off = 32; off >= 1; off >>= 1) contrib += __shfl_down(contrib, off, 64);
    if (lane == 0) *out = contrib / denom;
}

extern "C" void kernel_launch(void* const* d_in, const int* in_sizes, int n_in,
                              void* d_out, int out_size, void* d_ws, size_t ws_size,
                              hipStream_t stream)
{
    const float* pred   = (const float*)d_in[0];
    const float* target = (const float*)d_in[1];
    float* out = (float*)d_out;
    int n = in_sizes[0];

    float*    g_sums  = (float*)d_ws;
    unsigned* g_cnts  = (unsigned*)d_ws + 64;
    unsigned* g_total = (unsigned*)d_ws + 128;

    zero_ws_kernel<<<1, BLOCK, 0, stream>>>((unsigned*)d_ws);

    hist_kernel<<<GRID, BLOCK, 0, stream>>>(pred, target, n, g_sums, g_cnts, g_total);

    finalize_kernel<<<1, 64, 0, stream>>>(g_sums, g_cnts, g_total, out);
}